// Round 1
// baseline (418.478 us; speedup 1.0000x reference)
//
#include <hip/hip_runtime.h>

#define HASH_T    2097152u
#define HASH_MASK 2097151u
#define PRIME1 2654435761u
#define PRIME2 805459861u

struct F4 { float v[4]; };

__device__ __forceinline__ F4 ld4(const float* p){
    float4 t = *reinterpret_cast<const float4*>(p);
    F4 r; r.v[0]=t.x; r.v[1]=t.y; r.v[2]=t.z; r.v[3]=t.w; return r;
}

// ---------------- Kernel 1: hash-grid encode + erf reweight + mean over n ----
// one thread per (sample, level); writes feat[NS][40]
__global__ __launch_bounds__(256) void hash_encode_kernel(
    const float* __restrict__ means,   // [NS,6,3]
    const float* __restrict__ stds,    // [NS,6]
    const float* __restrict__ emb,     // [10, T, 4]
    float* __restrict__ feat,          // [NS,40]
    int NS)
{
    int gid = blockIdx.x * 256 + threadIdx.x;
    if (gid >= NS * 10) return;
    int l = gid / NS;
    int s = gid - l * NS;
    float r = (float)(16 << l);
    const float* __restrict__ embL = emb + (size_t)l * (size_t)HASH_T * 4u;

    float a0 = 0.f, a1 = 0.f, a2 = 0.f, a3 = 0.f;
    #pragma unroll
    for (int n = 0; n < 6; ++n) {
        const float* mp = means + ((size_t)s * 6 + n) * 3;
        float sd = stds[(size_t)s * 6 + n];
        // x01 = (m+1)*0.5 ; pos = x01*r - 0.5
        float px = (mp[0] + 1.0f) * 0.5f * r - 0.5f;
        float py = (mp[1] + 1.0f) * 0.5f * r - 0.5f;
        float pz = (mp[2] + 1.0f) * 0.5f * r - 0.5f;
        float fx = floorf(px), fy = floorf(py), fz = floorf(pz);
        float rx = px - fx, ry = py - fy, rz = pz - fz;
        int ix = (int)fx, iy = (int)fy, iz = (int)fz;
        unsigned hx[2] = { (unsigned)ix,            (unsigned)(ix + 1) };
        unsigned hy[2] = { (unsigned)iy * PRIME1,   (unsigned)(iy + 1) * PRIME1 };
        unsigned hz[2] = { (unsigned)iz * PRIME2,   (unsigned)(iz + 1) * PRIME2 };
        float wx[2] = { 1.0f - rx, rx };
        float wy[2] = { 1.0f - ry, ry };
        float wz[2] = { 1.0f - rz, rz };
        // erf anti-alias weight: erf(1/clip(sqrt(8*std^2*g^2),1e-10))
        float t8 = 8.0f * (sd * sd) * (r * r);
        float wl = erff(1.0f / fmaxf(sqrtf(t8), 1e-10f));

        float v0 = 0.f, v1 = 0.f, v2 = 0.f, v3 = 0.f;
        #pragma unroll
        for (int c = 0; c < 8; ++c) {
            int bx = (c >> 2) & 1, by = (c >> 1) & 1, bz = c & 1;
            unsigned idx = (hx[bx] ^ hy[by] ^ hz[bz]) & HASH_MASK;
            const float4 e = *reinterpret_cast<const float4*>(embL + (size_t)idx * 4u);
            float w = wx[bx] * wy[by] * wz[bz];
            v0 += w * e.x; v1 += w * e.y; v2 += w * e.z; v3 += w * e.w;
        }
        a0 += wl * v0; a1 += wl * v1; a2 += wl * v2; a3 += wl * v3;
    }
    const float inv6 = 1.0f / 6.0f;
    float4 o; o.x = a0 * inv6; o.y = a1 * inv6; o.z = a2 * inv6; o.w = a3 * inv6;
    *reinterpret_cast<float4*>(feat + (size_t)s * 40 + l * 4) = o;
}

// ---------------- Kernel 2: fused MLP, one block per ray (32 samples) --------
__global__ __launch_bounds__(256) void mlp_kernel(
    const float* __restrict__ feat,    // [NS,40]
    const float* __restrict__ vdirs,   // [B,3]
    const float* __restrict__ Wd0, const float* __restrict__ bd0,  // [40,64],[64]
    const float* __restrict__ Wd1, const float* __restrict__ bd1,  // [64,256],[256]
    const float* __restrict__ Wv0, const float* __restrict__ bv0,  // [283,256],[256]
    const float* __restrict__ Wv1, const float* __restrict__ bv1,  // [539,256],[256]
    const float* __restrict__ Wr,  const float* __restrict__ br,   // [256,3],[3]
    float* __restrict__ outD,          // [NS]
    float* __restrict__ outRGB)        // [NS,3]
{
    __shared__ float sFeat[32][44];   // feat, padded
    __shared__ float sX[32][260];     // bottleneck x (then reused for h3)
    __shared__ float sH[32][260];     // act0 (stride 68) then h2 (stride 260)
    __shared__ float sDe[27];
    float* sHf = &sH[0][0];

    const int t = threadIdx.x;
    const int b = blockIdx.x;
    const int base = b * 32;
    const int c4 = (t & 63) * 4;      // 4-column group for 256-wide layers
    const int sb = (t >> 6) * 8;      // 8-sample group

    // stage feat
    for (int i = t; i < 32 * 40; i += 256) {
        int s = i / 40, k = i - s * 40;
        sFeat[s][k] = feat[(size_t)(base + s) * 40 + k];
    }
    // dir encoding: [d(3), sin(xb)(12), sin(xb+pi/2)(12)]
    if (t < 27) {
        float d0 = vdirs[b * 3 + 0], d1 = vdirs[b * 3 + 1], d2 = vdirs[b * 3 + 2];
        float val;
        if (t < 3) {
            val = (t == 0) ? d0 : ((t == 1) ? d1 : d2);
        } else {
            int u = t - 3;
            int half = u / 12;
            int jk = u % 12;
            int j = jk / 3, k = jk % 3;
            float dk = (k == 0) ? d0 : ((k == 1) ? d1 : d2);
            float xb = dk * (float)(1 << j);
            val = sinf(half ? (xb + 1.57079632679489662f) : xb);
        }
        sDe[t] = val;
    }
    __syncthreads();

    // ---- L0: [32,40] @ [40,64] + bias, relu -> act0 (sHf stride 68)
    {
        const int c = t & 63;
        float acc[8];
        float bb = bd0[c];
        #pragma unroll
        for (int i = 0; i < 8; ++i) acc[i] = bb;
        #pragma unroll 2
        for (int k = 0; k < 40; k += 4) {
            float w0 = Wd0[(k + 0) * 64 + c];
            float w1 = Wd0[(k + 1) * 64 + c];
            float w2 = Wd0[(k + 2) * 64 + c];
            float w3 = Wd0[(k + 3) * 64 + c];
            #pragma unroll
            for (int i = 0; i < 8; ++i) {
                F4 xv = ld4(&sFeat[sb + i][k]);
                acc[i] += xv.v[0] * w0 + xv.v[1] * w1 + xv.v[2] * w2 + xv.v[3] * w3;
            }
        }
        #pragma unroll
        for (int i = 0; i < 8; ++i) sHf[(sb + i) * 68 + c] = fmaxf(acc[i], 0.0f);
    }
    __syncthreads();

    // ---- L1: [32,64] @ [64,256] + bias -> x in sX (no activation)
    {
        float acc[8][4];
        F4 bb = ld4(&bd1[c4]);
        #pragma unroll
        for (int i = 0; i < 8; ++i)
            #pragma unroll
            for (int j = 0; j < 4; ++j) acc[i][j] = bb.v[j];
        #pragma unroll 2
        for (int k = 0; k < 64; k += 4) {
            F4 w0 = ld4(&Wd1[(k + 0) * 256 + c4]);
            F4 w1 = ld4(&Wd1[(k + 1) * 256 + c4]);
            F4 w2 = ld4(&Wd1[(k + 2) * 256 + c4]);
            F4 w3 = ld4(&Wd1[(k + 3) * 256 + c4]);
            #pragma unroll
            for (int i = 0; i < 8; ++i) {
                F4 xv = ld4(&sHf[(sb + i) * 68 + k]);
                #pragma unroll
                for (int j = 0; j < 4; ++j)
                    acc[i][j] += xv.v[0] * w0.v[j] + xv.v[1] * w1.v[j]
                               + xv.v[2] * w2.v[j] + xv.v[3] * w3.v[j];
            }
        }
        #pragma unroll
        for (int i = 0; i < 8; ++i) {
            float4 o; o.x = acc[i][0]; o.y = acc[i][1]; o.z = acc[i][2]; o.w = acc[i][3];
            *reinterpret_cast<float4*>(&sX[sb + i][c4]) = o;
        }
    }
    __syncthreads();

    // density = softplus(x[...,0] - 1)
    if (t < 32) {
        float v = sX[t][0] - 1.0f;
        outD[base + t] = fmaxf(v, 0.0f) + log1pf(expf(-fabsf(v)));
    }

    // ---- L2: x_in=[x(256),de(27)] @ Wv0 + bias, relu -> h2 in sH (stride 260)
    {
        float acc[8][4];
        F4 bb = ld4(&bv0[c4]);
        #pragma unroll
        for (int i = 0; i < 8; ++i)
            #pragma unroll
            for (int j = 0; j < 4; ++j) acc[i][j] = bb.v[j];
        #pragma unroll 2
        for (int k = 0; k < 256; k += 4) {
            F4 w0 = ld4(&Wv0[(k + 0) * 256 + c4]);
            F4 w1 = ld4(&Wv0[(k + 1) * 256 + c4]);
            F4 w2 = ld4(&Wv0[(k + 2) * 256 + c4]);
            F4 w3 = ld4(&Wv0[(k + 3) * 256 + c4]);
            #pragma unroll
            for (int i = 0; i < 8; ++i) {
                F4 xv = ld4(&sX[sb + i][k]);
                #pragma unroll
                for (int j = 0; j < 4; ++j)
                    acc[i][j] += xv.v[0] * w0.v[j] + xv.v[1] * w1.v[j]
                               + xv.v[2] * w2.v[j] + xv.v[3] * w3.v[j];
            }
        }
        // de rows (sample-invariant partial sum)
        float pc[4] = {0.f, 0.f, 0.f, 0.f};
        #pragma unroll
        for (int k = 0; k < 27; ++k) {
            float dv = sDe[k];
            F4 w = ld4(&Wv0[(256 + k) * 256 + c4]);
            #pragma unroll
            for (int j = 0; j < 4; ++j) pc[j] += dv * w.v[j];
        }
        #pragma unroll
        for (int i = 0; i < 8; ++i) {
            float4 o;
            o.x = fmaxf(acc[i][0] + pc[0], 0.0f);
            o.y = fmaxf(acc[i][1] + pc[1], 0.0f);
            o.z = fmaxf(acc[i][2] + pc[2], 0.0f);
            o.w = fmaxf(acc[i][3] + pc[3], 0.0f);
            *reinterpret_cast<float4*>(&sH[sb + i][c4]) = o;
        }
    }
    __syncthreads();

    // ---- L3: [h2(256), x(256), de(27)] @ Wv1 + bias, relu -> h3 (into sX)
    {
        float acc[8][4];
        F4 bb = ld4(&bv1[c4]);
        #pragma unroll
        for (int i = 0; i < 8; ++i)
            #pragma unroll
            for (int j = 0; j < 4; ++j) acc[i][j] = bb.v[j];
        #pragma unroll 2
        for (int k = 0; k < 256; k += 4) {        // h2 part (rows 0..255)
            F4 w0 = ld4(&Wv1[(k + 0) * 256 + c4]);
            F4 w1 = ld4(&Wv1[(k + 1) * 256 + c4]);
            F4 w2 = ld4(&Wv1[(k + 2) * 256 + c4]);
            F4 w3 = ld4(&Wv1[(k + 3) * 256 + c4]);
            #pragma unroll
            for (int i = 0; i < 8; ++i) {
                F4 xv = ld4(&sH[sb + i][k]);
                #pragma unroll
                for (int j = 0; j < 4; ++j)
                    acc[i][j] += xv.v[0] * w0.v[j] + xv.v[1] * w1.v[j]
                               + xv.v[2] * w2.v[j] + xv.v[3] * w3.v[j];
            }
        }
        #pragma unroll 2
        for (int k = 0; k < 256; k += 4) {        // x part (rows 256..511)
            F4 w0 = ld4(&Wv1[(256 + k + 0) * 256 + c4]);
            F4 w1 = ld4(&Wv1[(256 + k + 1) * 256 + c4]);
            F4 w2 = ld4(&Wv1[(256 + k + 2) * 256 + c4]);
            F4 w3 = ld4(&Wv1[(256 + k + 3) * 256 + c4]);
            #pragma unroll
            for (int i = 0; i < 8; ++i) {
                F4 xv = ld4(&sX[sb + i][k]);
                #pragma unroll
                for (int j = 0; j < 4; ++j)
                    acc[i][j] += xv.v[0] * w0.v[j] + xv.v[1] * w1.v[j]
                               + xv.v[2] * w2.v[j] + xv.v[3] * w3.v[j];
            }
        }
        float pc[4] = {0.f, 0.f, 0.f, 0.f};       // de part (rows 512..538)
        #pragma unroll
        for (int k = 0; k < 27; ++k) {
            float dv = sDe[k];
            F4 w = ld4(&Wv1[(512 + k) * 256 + c4]);
            #pragma unroll
            for (int j = 0; j < 4; ++j) pc[j] += dv * w.v[j];
        }
        float h3[8][4];
        #pragma unroll
        for (int i = 0; i < 8; ++i)
            #pragma unroll
            for (int j = 0; j < 4; ++j) h3[i][j] = fmaxf(acc[i][j] + pc[j], 0.0f);
        __syncthreads();   // everyone done reading sX
        #pragma unroll
        for (int i = 0; i < 8; ++i) {
            float4 o; o.x = h3[i][0]; o.y = h3[i][1]; o.z = h3[i][2]; o.w = h3[i][3];
            *reinterpret_cast<float4*>(&sX[sb + i][c4]) = o;
        }
    }
    __syncthreads();

    // ---- L4: rgb = sigmoid(h3 @ Wr + br) * 1.002 - 0.001
    if (t < 96) {
        int s = t / 3, ch = t - s * 3;
        float a = br[ch];
        for (int k = 0; k < 256; ++k) a += sX[s][k] * Wr[k * 3 + ch];
        float sg = 1.0f / (1.0f + expf(-a));
        outRGB[(size_t)(base + s) * 3 + ch] = sg * 1.002f - 0.001f;
    }
}

extern "C" void kernel_launch(void* const* d_in, const int* in_sizes, int n_in,
                              void* d_out, int out_size, void* d_ws, size_t ws_size,
                              hipStream_t stream) {
    // input order: rand, means, stds, viewdirs, embeddings, Wd0,bd0, Wd1,bd1,
    //              Wv0,bv0, Wv1,bv1, Wr,br
    const float* means = (const float*)d_in[1];
    const float* stds_ = (const float*)d_in[2];
    const float* vdirs = (const float*)d_in[3];
    const float* emb   = (const float*)d_in[4];
    const float* Wd0 = (const float*)d_in[5];
    const float* bd0 = (const float*)d_in[6];
    const float* Wd1 = (const float*)d_in[7];
    const float* bd1 = (const float*)d_in[8];
    const float* Wv0 = (const float*)d_in[9];
    const float* bv0 = (const float*)d_in[10];
    const float* Wv1 = (const float*)d_in[11];
    const float* bv1 = (const float*)d_in[12];
    const float* Wr  = (const float*)d_in[13];
    const float* br  = (const float*)d_in[14];

    const int B  = in_sizes[3] / 3;   // 1024 rays
    const int NS = B * 32;            // 32768 samples

    float* feat = (float*)d_ws;       // [NS,40] f32 = 5.24 MB

    int total = NS * 10;
    hipLaunchKernelGGL(hash_encode_kernel, dim3((total + 255) / 256), dim3(256), 0, stream,
                       means, stds_, emb, feat, NS);

    float* outD   = (float*)d_out;        // [NS]
    float* outRGB = outD + NS;            // [NS,3]
    hipLaunchKernelGGL(mlp_kernel, dim3(B), dim3(256), 0, stream,
                       feat, vdirs, Wd0, bd0, Wd1, bd1, Wv0, bv0, Wv1, bv1, Wr, br,
                       outD, outRGB);
}

// Round 2
// 229.866 us; speedup vs baseline: 1.8205x; 1.8205x over previous
//
#include <hip/hip_runtime.h>

#define HASH_T    2097152u
#define HASH_MASK 2097151u
#define PRIME1 2654435761u
#define PRIME2 805459861u

typedef __attribute__((ext_vector_type(8))) short bf16x8;
typedef __attribute__((ext_vector_type(4))) float f32x4;
typedef __attribute__((ext_vector_type(4))) unsigned short us4;

__device__ __forceinline__ unsigned short bf16_hi(float x){
    unsigned u = __float_as_uint(x);
    return (unsigned short)((u + 0x7FFFu + ((u >> 16) & 1u)) >> 16);
}
__device__ __forceinline__ float bf16f(unsigned short h){
    return __uint_as_float((unsigned)h << 16);
}
__device__ __forceinline__ void split2(float x, unsigned short& h, unsigned short& l){
    h = bf16_hi(x);
    l = bf16_hi(x - bf16f(h));
}

// ---------------- Kernel 0: pack weights into MFMA fragment order (bf16 hi/lo)
// Layout per (kt,ct) pair: [hi 512 elems][lo 512 elems]; elem = lane*8 + j.
// A-operand (W^T): A[row=outcol=ct*16+(lane&15)][k=kt*32+8*(lane>>4)+j]
// pair index ranges: Wd0 0..7 (KT2,NCT4) | Wd1 8..39 (KT2,NCT16)
//                    Wv0 40..167 (KT8,NCT16) | Wv1 168..423 (KT16,NCT16)
__global__ __launch_bounds__(256) void pack_weights_kernel(
    const float* __restrict__ Wd0, const float* __restrict__ Wd1,
    const float* __restrict__ Wv0, const float* __restrict__ Wv1,
    unsigned short* __restrict__ pk)
{
    int tid = blockIdx.x * 256 + threadIdx.x;
    if (tid >= 424 * 512) return;
    int pair = tid >> 9;
    int li   = tid & 511;
    int lane = li >> 3, j = li & 7;
    int kq = ((lane >> 4) << 3) + j;   // 0..31 within kt
    int cl = lane & 15;
    float w;
    if (pair < 8) {                       // Wd0 [40,64], K padded to 64
        int idx = pair; int kt = idx >> 2, ct = idx & 3;
        int k = kt * 32 + kq, c = ct * 16 + cl;
        w = (k < 40) ? Wd0[k * 64 + c] : 0.0f;
    } else if (pair < 40) {               // Wd1 [64,256]
        int idx = pair - 8; int kt = idx >> 4, ct = idx & 15;
        int k = kt * 32 + kq, c = ct * 16 + cl;
        w = Wd1[k * 256 + c];
    } else if (pair < 168) {              // Wv0 rows 0..255 (x part)
        int idx = pair - 40; int kt = idx >> 4, ct = idx & 15;
        int k = kt * 32 + kq, c = ct * 16 + cl;
        w = Wv0[k * 256 + c];
    } else {                              // Wv1: packed k 0..255 = ref rows 256..511 (x),
        int idx = pair - 168;             //      packed k 256..511 = ref rows 0..255 (h2)
        int kt = idx >> 4, ct = idx & 15;
        int k = kt * 32 + kq, c = ct * 16 + cl;
        int refr = (k < 256) ? (k + 256) : (k - 256);
        w = Wv1[refr * 256 + c];
    }
    unsigned short h, l; split2(w, h, l);
    pk[(size_t)pair * 1024 + li]       = h;
    pk[(size_t)pair * 1024 + 512 + li] = l;
}

// ---------------- Kernel 1: hash-grid encode (unchanged, near gather roofline)
__global__ __launch_bounds__(256) void hash_encode_kernel(
    const float* __restrict__ means, const float* __restrict__ stds,
    const float* __restrict__ emb, float* __restrict__ feat, int NS)
{
    int gid = blockIdx.x * 256 + threadIdx.x;
    if (gid >= NS * 10) return;
    int l = gid / NS;
    int s = gid - l * NS;
    float r = (float)(16 << l);
    const float* __restrict__ embL = emb + (size_t)l * (size_t)HASH_T * 4u;

    float a0 = 0.f, a1 = 0.f, a2 = 0.f, a3 = 0.f;
    #pragma unroll
    for (int n = 0; n < 6; ++n) {
        const float* mp = means + ((size_t)s * 6 + n) * 3;
        float sd = stds[(size_t)s * 6 + n];
        float px = (mp[0] + 1.0f) * 0.5f * r - 0.5f;
        float py = (mp[1] + 1.0f) * 0.5f * r - 0.5f;
        float pz = (mp[2] + 1.0f) * 0.5f * r - 0.5f;
        float fx = floorf(px), fy = floorf(py), fz = floorf(pz);
        float rx = px - fx, ry = py - fy, rz = pz - fz;
        int ix = (int)fx, iy = (int)fy, iz = (int)fz;
        unsigned hx[2] = { (unsigned)ix,          (unsigned)(ix + 1) };
        unsigned hy[2] = { (unsigned)iy * PRIME1, (unsigned)(iy + 1) * PRIME1 };
        unsigned hz[2] = { (unsigned)iz * PRIME2, (unsigned)(iz + 1) * PRIME2 };
        float wx[2] = { 1.0f - rx, rx };
        float wy[2] = { 1.0f - ry, ry };
        float wz[2] = { 1.0f - rz, rz };
        float t8 = 8.0f * (sd * sd) * (r * r);
        float wl = erff(1.0f / fmaxf(sqrtf(t8), 1e-10f));
        float v0 = 0.f, v1 = 0.f, v2 = 0.f, v3 = 0.f;
        #pragma unroll
        for (int c = 0; c < 8; ++c) {
            int bx = (c >> 2) & 1, by = (c >> 1) & 1, bz = c & 1;
            unsigned idx = (hx[bx] ^ hy[by] ^ hz[bz]) & HASH_MASK;
            const float4 e = *reinterpret_cast<const float4*>(embL + (size_t)idx * 4u);
            float w = wx[bx] * wy[by] * wz[bz];
            v0 += w * e.x; v1 += w * e.y; v2 += w * e.z; v3 += w * e.w;
        }
        a0 += wl * v0; a1 += wl * v1; a2 += wl * v2; a3 += wl * v3;
    }
    const float inv6 = 1.0f / 6.0f;
    float4 o; o.x = a0 * inv6; o.y = a1 * inv6; o.z = a2 * inv6; o.w = a3 * inv6;
    *reinterpret_cast<float4*>(feat + (size_t)s * 40 + l * 4) = o;
}

// ---------------- Kernel 2: fused MFMA MLP, one block per ray --------------
// sA column regions (bf16 elems): [0..63] feat/act0 (h3 overwrites 0..255)
//                                 [64..319] x   [320..575] h2 ; rowstride 584
template<int KT, int NC>
__device__ __forceinline__ void gemm_layer(
    const unsigned short* __restrict__ pkBase, int NCT, int ct0, int kOff,
    const unsigned short (*Ahi)[584], const unsigned short (*Alo)[584],
    int lane, f32x4 acc[NC][2])
{
    const int r = lane & 15;
    const int kg = (lane >> 4) * 8;
    for (int kt = 0; kt < KT; ++kt) {
        const int ke = kOff + kt * 32 + kg;
        bf16x8 bh[2], bl[2];
        #pragma unroll
        for (int st = 0; st < 2; ++st) {
            bh[st] = *reinterpret_cast<const bf16x8*>(&Ahi[st * 16 + r][ke]);
            bl[st] = *reinterpret_cast<const bf16x8*>(&Alo[st * 16 + r][ke]);
        }
        #pragma unroll
        for (int ci = 0; ci < NC; ++ci) {
            const unsigned short* pf = pkBase + (size_t)(kt * NCT + ct0 + ci) * 1024 + lane * 8;
            bf16x8 ah = *reinterpret_cast<const bf16x8*>(pf);
            bf16x8 al = *reinterpret_cast<const bf16x8*>(pf + 512);
            #pragma unroll
            for (int st = 0; st < 2; ++st) {
                acc[ci][st] = __builtin_amdgcn_mfma_f32_16x16x32_bf16(ah, bh[st], acc[ci][st], 0, 0, 0);
                acc[ci][st] = __builtin_amdgcn_mfma_f32_16x16x32_bf16(ah, bl[st], acc[ci][st], 0, 0, 0);
                acc[ci][st] = __builtin_amdgcn_mfma_f32_16x16x32_bf16(al, bh[st], acc[ci][st], 0, 0, 0);
            }
        }
    }
}

template<int NC, bool RELU>
__device__ __forceinline__ void epilogue_store(
    f32x4 acc[NC][2], int ct0, int lane, const float* bias, int outOff,
    unsigned short (*Ahi)[584], unsigned short (*Alo)[584])
{
    const int r = lane & 15, g = lane >> 4;
    #pragma unroll
    for (int ci = 0; ci < NC; ++ci) {
        const int c0 = (ct0 + ci) * 16 + g * 4;
        const float4 bb = *reinterpret_cast<const float4*>(&bias[c0]);
        #pragma unroll
        for (int st = 0; st < 2; ++st) {
            const int s = st * 16 + r;
            float v[4] = { acc[ci][st][0] + bb.x, acc[ci][st][1] + bb.y,
                           acc[ci][st][2] + bb.z, acc[ci][st][3] + bb.w };
            us4 H, L;
            #pragma unroll
            for (int q = 0; q < 4; ++q) {
                float vv = RELU ? fmaxf(v[q], 0.0f) : v[q];
                unsigned short h, l; split2(vv, h, l);
                H[q] = h; L[q] = l;
            }
            *reinterpret_cast<us4*>(&Ahi[s][outOff + c0]) = H;
            *reinterpret_cast<us4*>(&Alo[s][outOff + c0]) = L;
        }
    }
}

__global__ __launch_bounds__(256, 2) void mlp_mfma_kernel(
    const float* __restrict__ feat, const float* __restrict__ vdirs,
    const unsigned short* __restrict__ pk,
    const float* __restrict__ bd0, const float* __restrict__ bd1,
    const float* __restrict__ Wv0, const float* __restrict__ bv0,
    const float* __restrict__ Wv1, const float* __restrict__ bv1,
    const float* __restrict__ Wr,  const float* __restrict__ br,
    float* __restrict__ outD, float* __restrict__ outRGB)
{
    __shared__ __align__(16) unsigned short sAhi[32][584];
    __shared__ __align__(16) unsigned short sAlo[32][584];
    __shared__ float sDe[32];
    __shared__ float sDv0[256];
    __shared__ float sDv1[256];
    __shared__ float sRed[32][8][3];

    const int t = threadIdx.x;
    const int lane = t & 63;
    const int w = t >> 6;
    const int b = blockIdx.x;
    const int base = b * 32;

    // ---- stage feat -> bf16 hi/lo, cols 0..39 (pad 40..63 = 0)
    {
        int s = t >> 3, kg = t & 7;
        float v[8];
        if (kg < 5) {
            const float* fp = feat + (size_t)(base + s) * 40 + kg * 8;
            #pragma unroll
            for (int q = 0; q < 8; ++q) v[q] = fp[q];
        } else {
            #pragma unroll
            for (int q = 0; q < 8; ++q) v[q] = 0.0f;
        }
        us4 H0, H1, L0v, L1v;
        #pragma unroll
        for (int q = 0; q < 4; ++q) {
            unsigned short h, l;
            split2(v[q], h, l);       H0[q] = h; L0v[q] = l;
            split2(v[q + 4], h, l);   H1[q] = h; L1v[q] = l;
        }
        *reinterpret_cast<us4*>(&sAhi[s][kg * 8])     = H0;
        *reinterpret_cast<us4*>(&sAhi[s][kg * 8 + 4]) = H1;
        *reinterpret_cast<us4*>(&sAlo[s][kg * 8])     = L0v;
        *reinterpret_cast<us4*>(&sAlo[s][kg * 8 + 4]) = L1v;
    }
    if (t < 27) {
        float d0 = vdirs[b * 3 + 0], d1 = vdirs[b * 3 + 1], d2 = vdirs[b * 3 + 2];
        float val;
        if (t < 3) val = (t == 0) ? d0 : ((t == 1) ? d1 : d2);
        else {
            int u = t - 3, half = u / 12, jk = u % 12;
            int j = jk / 3, k = jk % 3;
            float dk = (k == 0) ? d0 : ((k == 1) ? d1 : d2);
            float xb = dk * (float)(1 << j);
            val = sinf(half ? (xb + 1.57079632679489662f) : xb);
        }
        sDe[t] = val;
    }
    __syncthreads();

    // ---- per-block dir-enc + bias tables (rank-27 correction)
    {
        int c = t;
        float a0 = bv0[c], a1 = bv1[c];
        #pragma unroll
        for (int k = 0; k < 27; ++k) {
            float dv = sDe[k];
            a0 += dv * Wv0[(256 + k) * 256 + c];
            a1 += dv * Wv1[(512 + k) * 256 + c];
        }
        sDv0[c] = a0; sDv1[c] = a1;
    }

    // ---- L0: feat[32,64p] @ Wd0 -> act0 (cols 0..63), relu
    {
        f32x4 acc[1][2] = {};
        gemm_layer<2, 1>(pk, 4, w, 0, sAhi, sAlo, lane, acc);
        __syncthreads();                     // all feat reads done
        epilogue_store<1, true>(acc, w, lane, bd0, 0, sAhi, sAlo);
    }
    __syncthreads();

    // ---- L1: act0 @ Wd1 -> x (cols 64..319), no relu; density from col 0
    {
        f32x4 acc[4][2] = {};
        gemm_layer<2, 4>(pk + 8192, 16, w * 4, 0, sAhi, sAlo, lane, acc);
        if (w == 0 && (lane >> 4) == 0) {
            #pragma unroll
            for (int st = 0; st < 2; ++st) {
                float x0 = acc[0][st][0] + bd1[0];
                int s = st * 16 + (lane & 15);
                float vv = x0 - 1.0f;
                outD[base + s] = fmaxf(vv, 0.0f) + log1pf(expf(-fabsf(vv)));
            }
        }
        epilogue_store<4, false>(acc, w * 4, lane, bd1, 64, sAhi, sAlo);
    }
    __syncthreads();

    // ---- L2: x @ Wv0(x-rows) + sDv0 -> h2 (cols 320..575), relu
    {
        f32x4 acc[4][2] = {};
        gemm_layer<8, 4>(pk + 40960, 16, w * 4, 64, sAhi, sAlo, lane, acc);
        epilogue_store<4, true>(acc, w * 4, lane, sDv0, 320, sAhi, sAlo);
    }
    __syncthreads();

    // ---- L3: [x|h2] @ Wv1 + sDv1 -> h3 (cols 0..255), relu
    {
        f32x4 acc[4][2] = {};
        gemm_layer<16, 4>(pk + 172032, 16, w * 4, 64, sAhi, sAlo, lane, acc);
        __syncthreads();                     // x/h2 reads done before overwrite
        epilogue_store<4, true>(acc, w * 4, lane, sDv1, 0, sAhi, sAlo);
    }
    __syncthreads();

    // ---- L4: rgb = sigmoid(h3 @ Wr + br)*1.002 - 0.001 (k-partials + reduce)
    {
        int s = t & 31, jj = t >> 5;
        float p0 = 0.f, p1 = 0.f, p2 = 0.f;
        int k0 = jj * 32;
        #pragma unroll 2
        for (int q = 0; q < 4; ++q) {
            us4 vh[2], vl[2];
            *reinterpret_cast<uint4*>(vh) = *reinterpret_cast<const uint4*>(&sAhi[s][k0 + q * 8]);
            *reinterpret_cast<uint4*>(vl) = *reinterpret_cast<const uint4*>(&sAlo[s][k0 + q * 8]);
            #pragma unroll
            for (int e = 0; e < 8; ++e) {
                int k = k0 + q * 8 + e;
                float hv = bf16f(((const unsigned short*)vh)[e]) + bf16f(((const unsigned short*)vl)[e]);
                p0 += hv * Wr[k * 3 + 0];
                p1 += hv * Wr[k * 3 + 1];
                p2 += hv * Wr[k * 3 + 2];
            }
        }
        sRed[s][jj][0] = p0; sRed[s][jj][1] = p1; sRed[s][jj][2] = p2;
    }
    __syncthreads();
    if (t < 96) {
        int s = t & 31, ch = t >> 5;
        float a = br[ch];
        #pragma unroll
        for (int j = 0; j < 8; ++j) a += sRed[s][j][ch];
        float sg = 1.0f / (1.0f + expf(-a));
        outRGB[(size_t)(base + s) * 3 + ch] = sg * 1.002f - 0.001f;
    }
}

extern "C" void kernel_launch(void* const* d_in, const int* in_sizes, int n_in,
                              void* d_out, int out_size, void* d_ws, size_t ws_size,
                              hipStream_t stream) {
    const float* means = (const float*)d_in[1];
    const float* stds_ = (const float*)d_in[2];
    const float* vdirs = (const float*)d_in[3];
    const float* emb   = (const float*)d_in[4];
    const float* Wd0 = (const float*)d_in[5];
    const float* bd0 = (const float*)d_in[6];
    const float* Wd1 = (const float*)d_in[7];
    const float* bd1 = (const float*)d_in[8];
    const float* Wv0 = (const float*)d_in[9];
    const float* bv0 = (const float*)d_in[10];
    const float* Wv1 = (const float*)d_in[11];
    const float* bv1 = (const float*)d_in[12];
    const float* Wr  = (const float*)d_in[13];
    const float* br  = (const float*)d_in[14];

    const int B  = in_sizes[3] / 3;   // 1024 rays
    const int NS = B * 32;            // 32768 samples

    float* feat = (float*)d_ws;                                    // NS*40 f32
    unsigned short* pk = (unsigned short*)((char*)d_ws + (size_t)NS * 40 * 4);

    hipLaunchKernelGGL(pack_weights_kernel, dim3((424 * 512 + 255) / 256), dim3(256), 0, stream,
                       Wd0, Wd1, Wv0, Wv1, pk);

    int total = NS * 10;
    hipLaunchKernelGGL(hash_encode_kernel, dim3((total + 255) / 256), dim3(256), 0, stream,
                       means, stds_, emb, feat, NS);

    float* outD   = (float*)d_out;
    float* outRGB = outD + NS;
    hipLaunchKernelGGL(mlp_mfma_kernel, dim3(B), dim3(256), 0, stream,
                       feat, vdirs, pk, bd0, bd1, Wv0, bv0, Wv1, bv1, Wr, br,
                       outD, outRGB);
}

// Round 3
// 209.249 us; speedup vs baseline: 1.9999x; 1.0985x over previous
//
#include <hip/hip_runtime.h>

#define HASH_T    2097152u
#define HASH_MASK 2097151u
#define PRIME1 2654435761u
#define PRIME2 805459861u

typedef __attribute__((ext_vector_type(8))) short bf16x8;
typedef __attribute__((ext_vector_type(4))) float f32x4;
typedef __attribute__((ext_vector_type(4))) unsigned short us4;

__device__ __forceinline__ unsigned short bf16_hi(float x){
    unsigned u = __float_as_uint(x);
    return (unsigned short)((u + 0x7FFFu + ((u >> 16) & 1u)) >> 16);
}
__device__ __forceinline__ float bf16f(unsigned short h){
    return __uint_as_float((unsigned)h << 16);
}
__device__ __forceinline__ void split2(float x, unsigned short& h, unsigned short& l){
    h = bf16_hi(x);
    l = bf16_hi(x - bf16f(h));
}

// ---------------- Kernel 0: pack weights into MFMA fragment order (bf16 hi/lo)
__global__ __launch_bounds__(256) void pack_weights_kernel(
    const float* __restrict__ Wd0, const float* __restrict__ Wd1,
    const float* __restrict__ Wv0, const float* __restrict__ Wv1,
    unsigned short* __restrict__ pk)
{
    int tid = blockIdx.x * 256 + threadIdx.x;
    if (tid >= 424 * 512) return;
    int pair = tid >> 9;
    int li   = tid & 511;
    int lane = li >> 3, j = li & 7;
    int kq = ((lane >> 4) << 3) + j;
    int cl = lane & 15;
    float w;
    if (pair < 8) {                       // Wd0 [40,64], K padded to 64
        int idx = pair; int kt = idx >> 2, ct = idx & 3;
        int k = kt * 32 + kq, c = ct * 16 + cl;
        w = (k < 40) ? Wd0[k * 64 + c] : 0.0f;
    } else if (pair < 40) {               // Wd1 [64,256]
        int idx = pair - 8; int kt = idx >> 4, ct = idx & 15;
        int k = kt * 32 + kq, c = ct * 16 + cl;
        w = Wd1[k * 256 + c];
    } else if (pair < 168) {              // Wv0 rows 0..255 (x part)
        int idx = pair - 40; int kt = idx >> 4, ct = idx & 15;
        int k = kt * 32 + kq, c = ct * 16 + cl;
        w = Wv0[k * 256 + c];
    } else {                              // Wv1: packed k 0..255 = ref rows 256..511 (x)
        int idx = pair - 168;             //      packed k 256..511 = ref rows 0..255 (h2)
        int kt = idx >> 4, ct = idx & 15;
        int k = kt * 32 + kq, c = ct * 16 + cl;
        int refr = (k < 256) ? (k + 256) : (k - 256);
        w = Wv1[refr * 256 + c];
    }
    unsigned short h, l; split2(w, h, l);
    pk[(size_t)pair * 1024 + li]       = h;
    pk[(size_t)pair * 1024 + 512 + li] = l;
}

// ---------------- Kernel 1: hash-grid encode, wave-per-(sample,level) --------
// lane = n*8 + corner; one gather instruction per task; butterfly reduce.
__global__ __launch_bounds__(256, 4) void hash_encode_wave(
    const float* __restrict__ means, const float* __restrict__ stds,
    const float* __restrict__ emb, float* __restrict__ feat, int NS)
{
    const int lane = threadIdx.x & 63;
    const int gwave = (blockIdx.x * 256 + threadIdx.x) >> 6;
    const int n = lane >> 3;
    const int c = lane & 7;
    const int bx = (c >> 2) & 1, by = (c >> 1) & 1, bz = c & 1;
    const bool act = (n < 6);
    const float inv6 = 1.0f / 6.0f;

    int s0 = gwave * 4;
    for (int si = 0; si < 4; ++si) {
        int s = s0 + si;
        if (s >= NS) return;
        float mx = 0.f, my = 0.f, mz = 0.f, sd = 1.0f;
        if (act) {
            const float* mp = means + ((size_t)s * 6 + n) * 3;
            mx = mp[0]; my = mp[1]; mz = mp[2];
            sd = stds[(size_t)s * 6 + n];
        }
        float sd2_8 = 8.0f * sd * sd;
        #pragma unroll 2
        for (int l = 0; l < 10; ++l) {
            float r = (float)(16 << l);
            float px = (mx + 1.0f) * 0.5f * r - 0.5f;
            float py = (my + 1.0f) * 0.5f * r - 0.5f;
            float pz = (mz + 1.0f) * 0.5f * r - 0.5f;
            float fx = floorf(px), fy = floorf(py), fz = floorf(pz);
            float rx = px - fx, ry = py - fy, rz = pz - fz;
            int ix = (int)fx + bx, iy = (int)fy + by, iz = (int)fz + bz;
            unsigned h = (unsigned)ix ^ ((unsigned)iy * PRIME1) ^ ((unsigned)iz * PRIME2);
            unsigned idx = h & HASH_MASK;
            float wx = bx ? rx : 1.0f - rx;
            float wy = by ? ry : 1.0f - ry;
            float wz = bz ? rz : 1.0f - rz;
            float wl = erff(1.0f / fmaxf(sqrtf(sd2_8 * r * r), 1e-10f));
            float w = act ? (wx * wy * wz) * wl : 0.0f;
            const float4 e = *reinterpret_cast<const float4*>(
                emb + ((size_t)l * HASH_T + idx) * 4u);
            float a0 = w * e.x, a1 = w * e.y, a2 = w * e.z, a3 = w * e.w;
            #pragma unroll
            for (int m = 1; m < 64; m <<= 1) {
                a0 += __shfl_xor(a0, m);
                a1 += __shfl_xor(a1, m);
                a2 += __shfl_xor(a2, m);
                a3 += __shfl_xor(a3, m);
            }
            if (lane == 0) {
                float4 o; o.x = a0 * inv6; o.y = a1 * inv6; o.z = a2 * inv6; o.w = a3 * inv6;
                *reinterpret_cast<float4*>(feat + (size_t)s * 40 + l * 4) = o;
            }
        }
    }
}

// ---------------- Kernel 2: fused MFMA MLP, 64 samples (2 rays) per block ----
// sA cols: [0..63] feat/act0 (h3 overwrites 0..255), [64..319] x, [320..575] h2
template<int KT, int NC>
__device__ __forceinline__ void gemm64(
    const unsigned short* __restrict__ pkBase, int NCT, int ct0, int kOff,
    const unsigned short (*Ahi)[584], const unsigned short (*Alo)[584],
    int lane, f32x4 acc[NC][4])
{
    const int r = lane & 15;
    const int kg = (lane >> 4) * 8;
    bf16x8 ah[NC], al[NC];
    #pragma unroll
    for (int ci = 0; ci < NC; ++ci) {
        const unsigned short* pf = pkBase + (size_t)(ct0 + ci) * 1024 + (size_t)lane * 8;
        ah[ci] = *reinterpret_cast<const bf16x8*>(pf);
        al[ci] = *reinterpret_cast<const bf16x8*>(pf + 512);
    }
    #pragma unroll
    for (int kt = 0; kt < KT; ++kt) {
        bf16x8 ahn[NC], aln[NC];
        if (kt + 1 < KT) {
            #pragma unroll
            for (int ci = 0; ci < NC; ++ci) {
                const unsigned short* pf = pkBase
                    + (size_t)((kt + 1) * NCT + ct0 + ci) * 1024 + (size_t)lane * 8;
                ahn[ci] = *reinterpret_cast<const bf16x8*>(pf);
                aln[ci] = *reinterpret_cast<const bf16x8*>(pf + 512);
            }
        }
        const int ke = kOff + kt * 32 + kg;
        #pragma unroll
        for (int st = 0; st < 4; ++st) {
            bf16x8 bh = *reinterpret_cast<const bf16x8*>(&Ahi[st * 16 + r][ke]);
            bf16x8 bl = *reinterpret_cast<const bf16x8*>(&Alo[st * 16 + r][ke]);
            #pragma unroll
            for (int ci = 0; ci < NC; ++ci) {
                acc[ci][st] = __builtin_amdgcn_mfma_f32_16x16x32_bf16(ah[ci], bh, acc[ci][st], 0, 0, 0);
                acc[ci][st] = __builtin_amdgcn_mfma_f32_16x16x32_bf16(ah[ci], bl, acc[ci][st], 0, 0, 0);
                acc[ci][st] = __builtin_amdgcn_mfma_f32_16x16x32_bf16(al[ci], bh, acc[ci][st], 0, 0, 0);
            }
        }
        #pragma unroll
        for (int ci = 0; ci < NC; ++ci) { ah[ci] = ahn[ci]; al[ci] = aln[ci]; }
    }
}

template<int NC, bool RELU>
__device__ __forceinline__ void epi64(
    f32x4 acc[NC][4], int ct0, int lane,
    const float* biasA, const float* biasB, int outOff,
    unsigned short (*Ahi)[584], unsigned short (*Alo)[584])
{
    const int r = lane & 15, g = lane >> 4;
    #pragma unroll
    for (int ci = 0; ci < NC; ++ci) {
        const int c0 = (ct0 + ci) * 16 + g * 4;
        #pragma unroll
        for (int st = 0; st < 4; ++st) {
            const float* bp = (st < 2) ? biasA : biasB;
            const float4 bb = *reinterpret_cast<const float4*>(&bp[c0]);
            const int s = st * 16 + r;
            float v[4] = { acc[ci][st][0] + bb.x, acc[ci][st][1] + bb.y,
                           acc[ci][st][2] + bb.z, acc[ci][st][3] + bb.w };
            us4 H, L;
            #pragma unroll
            for (int q = 0; q < 4; ++q) {
                float vv = RELU ? fmaxf(v[q], 0.0f) : v[q];
                unsigned short h, l; split2(vv, h, l);
                H[q] = h; L[q] = l;
            }
            *reinterpret_cast<us4*>(&Ahi[s][outOff + c0]) = H;
            *reinterpret_cast<us4*>(&Alo[s][outOff + c0]) = L;
        }
    }
}

__global__ __launch_bounds__(512, 2) void mlp_mfma_kernel(
    const float* __restrict__ feat, const float* __restrict__ vdirs,
    const unsigned short* __restrict__ pk,
    const float* __restrict__ bd0, const float* __restrict__ bd1,
    const float* __restrict__ Wv0, const float* __restrict__ bv0,
    const float* __restrict__ Wv1, const float* __restrict__ bv1,
    const float* __restrict__ Wr,  const float* __restrict__ br,
    float* __restrict__ outD, float* __restrict__ outRGB)
{
    __shared__ __align__(16) unsigned short sAhi[64][584];
    __shared__ __align__(16) unsigned short sAlo[64][584];
    __shared__ float sDe[2][32];
    __shared__ float sDv0[2][256];
    __shared__ float sDv1[2][256];

    const int t = threadIdx.x;
    const int lane = t & 63;
    const int w = t >> 6;
    const int b = blockIdx.x;
    const int base = b * 64;

    // ---- stage feat -> bf16 hi/lo, cols 0..39 (pad 40..63 = 0)
    {
        int s = t >> 3, kg = t & 7;
        float v[8];
        if (kg < 5) {
            const float4 f0 = *reinterpret_cast<const float4*>(feat + (size_t)(base + s) * 40 + kg * 8);
            const float4 f1 = *reinterpret_cast<const float4*>(feat + (size_t)(base + s) * 40 + kg * 8 + 4);
            v[0]=f0.x; v[1]=f0.y; v[2]=f0.z; v[3]=f0.w;
            v[4]=f1.x; v[5]=f1.y; v[6]=f1.z; v[7]=f1.w;
        } else {
            #pragma unroll
            for (int q = 0; q < 8; ++q) v[q] = 0.0f;
        }
        us4 H0, H1, L0v, L1v;
        #pragma unroll
        for (int q = 0; q < 4; ++q) {
            unsigned short h, l;
            split2(v[q], h, l);       H0[q] = h; L0v[q] = l;
            split2(v[q + 4], h, l);   H1[q] = h; L1v[q] = l;
        }
        *reinterpret_cast<us4*>(&sAhi[s][kg * 8])     = H0;
        *reinterpret_cast<us4*>(&sAhi[s][kg * 8 + 4]) = H1;
        *reinterpret_cast<us4*>(&sAlo[s][kg * 8])     = L0v;
        *reinterpret_cast<us4*>(&sAlo[s][kg * 8 + 4]) = L1v;
    }
    if (t < 54) {
        int ry = (t >= 27) ? 1 : 0;
        int u = t - ry * 27;
        float d0 = vdirs[(2 * b + ry) * 3 + 0];
        float d1 = vdirs[(2 * b + ry) * 3 + 1];
        float d2 = vdirs[(2 * b + ry) * 3 + 2];
        float val;
        if (u < 3) val = (u == 0) ? d0 : ((u == 1) ? d1 : d2);
        else {
            int v2 = u - 3, half = v2 / 12, jk = v2 % 12;
            int j = jk / 3, k = jk % 3;
            float dk = (k == 0) ? d0 : ((k == 1) ? d1 : d2);
            float xb = dk * (float)(1 << j);
            val = sinf(half ? (xb + 1.57079632679489662f) : xb);
        }
        sDe[ry][u] = val;
    }
    __syncthreads();

    // ---- per-ray dir-enc + bias tables (rank-27 correction)
    {
        int c = t & 255, ry = t >> 8;
        float a0 = bv0[c], a1 = bv1[c];
        #pragma unroll
        for (int k = 0; k < 27; ++k) {
            float dv = sDe[ry][k];
            a0 += dv * Wv0[(256 + k) * 256 + c];
            a1 += dv * Wv1[(512 + k) * 256 + c];
        }
        sDv0[ry][c] = a0; sDv1[ry][c] = a1;
    }

    // ---- L0: feat[64,64p] @ Wd0 -> act0 (cols 0..63), relu  (waves 0..3)
    {
        f32x4 acc[1][4] = {};
        if (w < 4) gemm64<2, 1>(pk, 4, w, 0, sAhi, sAlo, lane, acc);
        __syncthreads();
        if (w < 4) epi64<1, true>(acc, w, lane, bd0, bd0, 0, sAhi, sAlo);
    }
    __syncthreads();

    // ---- L1: act0 @ Wd1 -> x (cols 64..319); density from col 0
    {
        f32x4 acc[2][4] = {};
        gemm64<2, 2>(pk + 8192, 16, w * 2, 0, sAhi, sAlo, lane, acc);
        if (w == 0 && (lane >> 4) == 0) {
            #pragma unroll
            for (int st = 0; st < 4; ++st) {
                float x0 = acc[0][st][0] + bd1[0];
                int s = st * 16 + (lane & 15);
                float vv = x0 - 1.0f;
                outD[base + s] = fmaxf(vv, 0.0f) + log1pf(expf(-fabsf(vv)));
            }
        }
        epi64<2, false>(acc, w * 2, lane, bd1, bd1, 64, sAhi, sAlo);
    }
    __syncthreads();

    // ---- L2: x @ Wv0(x-rows) + sDv0 -> h2 (cols 320..575), relu
    {
        f32x4 acc[2][4] = {};
        gemm64<8, 2>(pk + 40960, 16, w * 2, 64, sAhi, sAlo, lane, acc);
        epi64<2, true>(acc, w * 2, lane, sDv0[0], sDv0[1], 320, sAhi, sAlo);
    }
    __syncthreads();

    // ---- L3: [x|h2] @ Wv1 + sDv1 -> h3 (cols 0..255), relu
    {
        f32x4 acc[2][4] = {};
        gemm64<16, 2>(pk + 172032, 16, w * 2, 64, sAhi, sAlo, lane, acc);
        __syncthreads();
        epi64<2, true>(acc, w * 2, lane, sDv1[0], sDv1[1], 0, sAhi, sAlo);
    }
    __syncthreads();

    // ---- L4: rgb = sigmoid(h3 @ Wr + br)*1.002 - 0.001
    {
        int s = t >> 3, j = t & 7, k0 = j * 32;
        float p0 = 0.f, p1 = 0.f, p2 = 0.f;
        #pragma unroll 2
        for (int q = 0; q < 4; ++q) {
            us4 vh[2], vl[2];
            *reinterpret_cast<uint4*>(vh) = *reinterpret_cast<const uint4*>(&sAhi[s][k0 + q * 8]);
            *reinterpret_cast<uint4*>(vl) = *reinterpret_cast<const uint4*>(&sAlo[s][k0 + q * 8]);
            #pragma unroll
            for (int e = 0; e < 8; ++e) {
                int k = k0 + q * 8 + e;
                float hv = bf16f(((const unsigned short*)vh)[e]) + bf16f(((const unsigned short*)vl)[e]);
                p0 += hv * Wr[k * 3 + 0];
                p1 += hv * Wr[k * 3 + 1];
                p2 += hv * Wr[k * 3 + 2];
            }
        }
        #pragma unroll
        for (int m = 1; m < 8; m <<= 1) {
            p0 += __shfl_xor(p0, m);
            p1 += __shfl_xor(p1, m);
            p2 += __shfl_xor(p2, m);
        }
        if (j < 3) {
            float a = ((j == 0) ? p0 : (j == 1) ? p1 : p2) + br[j];
            float sg = 1.0f / (1.0f + expf(-a));
            outRGB[(size_t)(base + s) * 3 + j] = sg * 1.002f - 0.001f;
        }
    }
}

extern "C" void kernel_launch(void* const* d_in, const int* in_sizes, int n_in,
                              void* d_out, int out_size, void* d_ws, size_t ws_size,
                              hipStream_t stream) {
    const float* means = (const float*)d_in[1];
    const float* stds_ = (const float*)d_in[2];
    const float* vdirs = (const float*)d_in[3];
    const float* emb   = (const float*)d_in[4];
    const float* Wd0 = (const float*)d_in[5];
    const float* bd0 = (const float*)d_in[6];
    const float* Wd1 = (const float*)d_in[7];
    const float* bd1 = (const float*)d_in[8];
    const float* Wv0 = (const float*)d_in[9];
    const float* bv0 = (const float*)d_in[10];
    const float* Wv1 = (const float*)d_in[11];
    const float* bv1 = (const float*)d_in[12];
    const float* Wr  = (const float*)d_in[13];
    const float* br  = (const float*)d_in[14];

    const int B  = in_sizes[3] / 3;   // 1024 rays
    const int NS = B * 32;            // 32768 samples

    float* feat = (float*)d_ws;                                    // NS*40 f32
    unsigned short* pk = (unsigned short*)((char*)d_ws + (size_t)NS * 40 * 4);

    hipLaunchKernelGGL(pack_weights_kernel, dim3((424 * 512 + 255) / 256), dim3(256), 0, stream,
                       Wd0, Wd1, Wv0, Wv1, pk);

    int nwaves = (NS + 3) / 4;
    hipLaunchKernelGGL(hash_encode_wave, dim3((nwaves * 64 + 255) / 256), dim3(256), 0, stream,
                       means, stds_, emb, feat, NS);

    float* outD   = (float*)d_out;
    float* outRGB = outD + NS;
    hipLaunchKernelGGL(mlp_mfma_kernel, dim3(NS / 64), dim3(512), 0, stream,
                       feat, vdirs, pk, bd0, bd1, Wv0, bv0, Wv1, bv1, Wr, br,
                       outD, outRGB);
}

// Round 5
// 191.435 us; speedup vs baseline: 2.1860x; 1.0931x over previous
//
#include <hip/hip_runtime.h>

#define HASH_T    2097152u
#define HASH_MASK 2097151u
#define PRIME1 2654435761u
#define PRIME2 805459861u

typedef __attribute__((ext_vector_type(8))) short bf16x8;
typedef __attribute__((ext_vector_type(4))) float f32x4;
typedef __attribute__((ext_vector_type(4))) unsigned short us4;

#define LDS_STRIDE 328   // cols 0..63 feat/act0, 64..319 x->h2->h3, pad 8

__device__ __forceinline__ unsigned short bf16_hi(float x){
    unsigned u = __float_as_uint(x);
    return (unsigned short)((u + 0x7FFFu + ((u >> 16) & 1u)) >> 16);
}
__device__ __forceinline__ float bf16f(unsigned short h){
    return __uint_as_float((unsigned)h << 16);
}
__device__ __forceinline__ void split2(float x, unsigned short& h, unsigned short& l){
    h = bf16_hi(x);
    l = bf16_hi(x - bf16f(h));
}

// ---------------- Kernel 0: pack weights into MFMA fragment order (bf16 hi/lo)
__global__ __launch_bounds__(256) void pack_weights_kernel(
    const float* __restrict__ Wd0, const float* __restrict__ Wd1,
    const float* __restrict__ Wv0, const float* __restrict__ Wv1,
    unsigned short* __restrict__ pk)
{
    int tid = blockIdx.x * 256 + threadIdx.x;
    if (tid >= 424 * 512) return;
    int pair = tid >> 9;
    int li   = tid & 511;
    int lane = li >> 3, j = li & 7;
    int kq = ((lane >> 4) << 3) + j;
    int cl = lane & 15;
    float w;
    if (pair < 8) {                       // Wd0 [40,64], K padded to 64
        int idx = pair; int kt = idx >> 2, ct = idx & 3;
        int k = kt * 32 + kq, c = ct * 16 + cl;
        w = (k < 40) ? Wd0[k * 64 + c] : 0.0f;
    } else if (pair < 40) {               // Wd1 [64,256]
        int idx = pair - 8; int kt = idx >> 4, ct = idx & 15;
        int k = kt * 32 + kq, c = ct * 16 + cl;
        w = Wd1[k * 256 + c];
    } else if (pair < 168) {              // Wv0 rows 0..255 (x part)
        int idx = pair - 40; int kt = idx >> 4, ct = idx & 15;
        int k = kt * 32 + kq, c = ct * 16 + cl;
        w = Wv0[k * 256 + c];
    } else {                              // Wv1: packed k 0..255 = ref rows 256..511 (x)
        int idx = pair - 168;             //      packed k 256..511 = ref rows 0..255 (h2)
        int kt = idx >> 4, ct = idx & 15;
        int k = kt * 32 + kq, c = ct * 16 + cl;
        int refr = (k < 256) ? (k + 256) : (k - 256);
        w = Wv1[refr * 256 + c];
    }
    unsigned short h, l; split2(w, h, l);
    pk[(size_t)pair * 1024 + li]       = h;
    pk[(size_t)pair * 1024 + 512 + li] = l;
}

// ---------------- fused kernel helpers --------------------------------------
template<int KT, int NC>
__device__ __forceinline__ void gemm32(
    const unsigned short* __restrict__ pkBase, int NCT, int ct0, int kOff,
    const unsigned short (*Ahi)[LDS_STRIDE], const unsigned short (*Alo)[LDS_STRIDE],
    int lane, f32x4 acc[NC][2])
{
    const int r = lane & 15;
    const int kg = (lane >> 4) * 8;
    bf16x8 ah[NC], al[NC];
    #pragma unroll
    for (int ci = 0; ci < NC; ++ci) {
        const unsigned short* pf = pkBase + (size_t)(ct0 + ci) * 1024 + (size_t)lane * 8;
        ah[ci] = *reinterpret_cast<const bf16x8*>(pf);
        al[ci] = *reinterpret_cast<const bf16x8*>(pf + 512);
    }
    #pragma unroll
    for (int kt = 0; kt < KT; ++kt) {
        bf16x8 ahn[NC], aln[NC];
        if (kt + 1 < KT) {
            #pragma unroll
            for (int ci = 0; ci < NC; ++ci) {
                const unsigned short* pf = pkBase
                    + (size_t)((kt + 1) * NCT + ct0 + ci) * 1024 + (size_t)lane * 8;
                ahn[ci] = *reinterpret_cast<const bf16x8*>(pf);
                aln[ci] = *reinterpret_cast<const bf16x8*>(pf + 512);
            }
        }
        const int ke = kOff + kt * 32 + kg;
        bf16x8 bh[2], bl[2];
        #pragma unroll
        for (int st = 0; st < 2; ++st) {
            bh[st] = *reinterpret_cast<const bf16x8*>(&Ahi[st * 16 + r][ke]);
            bl[st] = *reinterpret_cast<const bf16x8*>(&Alo[st * 16 + r][ke]);
        }
        #pragma unroll
        for (int ci = 0; ci < NC; ++ci) {
            #pragma unroll
            for (int st = 0; st < 2; ++st) {
                acc[ci][st] = __builtin_amdgcn_mfma_f32_16x16x32_bf16(ah[ci], bh[st], acc[ci][st], 0, 0, 0);
                acc[ci][st] = __builtin_amdgcn_mfma_f32_16x16x32_bf16(ah[ci], bl[st], acc[ci][st], 0, 0, 0);
                acc[ci][st] = __builtin_amdgcn_mfma_f32_16x16x32_bf16(al[ci], bh[st], acc[ci][st], 0, 0, 0);
            }
        }
        if (kt + 1 < KT) {
            #pragma unroll
            for (int ci = 0; ci < NC; ++ci) { ah[ci] = ahn[ci]; al[ci] = aln[ci]; }
        }
    }
}

template<int NC, bool RELU>
__device__ __forceinline__ void epi32(
    f32x4 acc[NC][2], int ct0, int lane, const float* bias, int outOff,
    unsigned short (*Ahi)[LDS_STRIDE], unsigned short (*Alo)[LDS_STRIDE])
{
    const int r = lane & 15, g = lane >> 4;
    #pragma unroll
    for (int ci = 0; ci < NC; ++ci) {
        const int c0 = (ct0 + ci) * 16 + g * 4;
        const float4 bb = *reinterpret_cast<const float4*>(&bias[c0]);
        #pragma unroll
        for (int st = 0; st < 2; ++st) {
            const int s = st * 16 + r;
            float v[4] = { acc[ci][st][0] + bb.x, acc[ci][st][1] + bb.y,
                           acc[ci][st][2] + bb.z, acc[ci][st][3] + bb.w };
            us4 H, L;
            #pragma unroll
            for (int q = 0; q < 4; ++q) {
                float vv = RELU ? fmaxf(v[q], 0.0f) : v[q];
                unsigned short h, l; split2(vv, h, l);
                H[q] = h; L[q] = l;
            }
            *reinterpret_cast<us4*>(&Ahi[s][outOff + c0]) = H;
            *reinterpret_cast<us4*>(&Alo[s][outOff + c0]) = L;
        }
    }
}

// ---------------- Kernel 1: fused hash-grid + MLP, one ray (32 samples)/block
__global__ __launch_bounds__(256, 3) void zip_fused_kernel(
    const float* __restrict__ means, const float* __restrict__ stds,
    const float* __restrict__ vdirs, const float* __restrict__ emb,
    const unsigned short* __restrict__ pk,
    const float* __restrict__ bd0, const float* __restrict__ bd1,
    const float* __restrict__ Wv0, const float* __restrict__ bv0,
    const float* __restrict__ Wv1, const float* __restrict__ bv1,
    const float* __restrict__ Wr,  const float* __restrict__ br,
    float* __restrict__ outD, float* __restrict__ outRGB)
{
    __shared__ __align__(16) unsigned short sAhi[32][LDS_STRIDE];
    __shared__ __align__(16) unsigned short sAlo[32][LDS_STRIDE];
    __shared__ float sDe[32];
    __shared__ float sDv0[256];
    __shared__ float sDv1[256];

    const int t = threadIdx.x;
    const int lane = t & 63;
    const int w = t >> 6;
    const int b = blockIdx.x;          // ray index
    const int base = b * 32;

    // ---- phase 0: zero-pad feat cols 40..63; dir encoding
    if (t < 192) {
        int s = t / 6, j = t - s * 6;
        us4 z = {0, 0, 0, 0};
        *reinterpret_cast<us4*>(&sAhi[s][40 + j * 4]) = z;
        *reinterpret_cast<us4*>(&sAlo[s][40 + j * 4]) = z;
    }
    if (t < 27) {
        float d0 = vdirs[b * 3 + 0], d1 = vdirs[b * 3 + 1], d2 = vdirs[b * 3 + 2];
        float val;
        if (t < 3) val = (t == 0) ? d0 : ((t == 1) ? d1 : d2);
        else {
            int u = t - 3, half = u / 12, jk = u % 12;
            int j = jk / 3, k = jk % 3;
            float dk = (k == 0) ? d0 : ((k == 1) ? d1 : d2);
            float xb = dk * (float)(1 << j);
            val = sinf(half ? (xb + 1.57079632679489662f) : xb);
        }
        sDe[t] = val;
    }
    __syncthreads();

    // ---- phase 1: hash gather; thread = (sample s = t>>3, multisample n = t&7)
    {
        const int s = t >> 3, n = t & 7;
        const bool act = (n < 6);
        float mx = 0.f, my = 0.f, mz = 0.f, sd2_8 = 0.f;
        if (act) {
            const float* mp = means + ((size_t)(base + s) * 6 + n) * 3;
            mx = mp[0]; my = mp[1]; mz = mp[2];
            float sd = stds[(size_t)(base + s) * 6 + n];
            sd2_8 = 8.0f * sd * sd;
        }
        const float inv6 = 1.0f / 6.0f;
        #pragma unroll 2
        for (int l = 0; l < 10; ++l) {
            float r = (float)(16 << l);
            float a0 = 0.f, a1 = 0.f, a2 = 0.f, a3 = 0.f;
            if (act) {
                float px = (mx + 1.0f) * 0.5f * r - 0.5f;
                float py = (my + 1.0f) * 0.5f * r - 0.5f;
                float pz = (mz + 1.0f) * 0.5f * r - 0.5f;
                float fx = floorf(px), fy = floorf(py), fz = floorf(pz);
                float rx = px - fx, ry = py - fy, rz = pz - fz;
                int ix = (int)fx, iy = (int)fy, iz = (int)fz;
                unsigned hx[2] = { (unsigned)ix,          (unsigned)(ix + 1) };
                unsigned hy[2] = { (unsigned)iy * PRIME1, (unsigned)(iy + 1) * PRIME1 };
                unsigned hz[2] = { (unsigned)iz * PRIME2, (unsigned)(iz + 1) * PRIME2 };
                float wx[2] = { 1.0f - rx, rx };
                float wy[2] = { 1.0f - ry, ry };
                float wz[2] = { 1.0f - rz, rz };
                float wl = erff(1.0f / fmaxf(sqrtf(sd2_8 * r * r), 1e-10f));
                #pragma unroll
                for (int c = 0; c < 8; ++c) {
                    int cx = (c >> 2) & 1, cy = (c >> 1) & 1, cz = c & 1;
                    unsigned idx = (hx[cx] ^ hy[cy] ^ hz[cz]) & HASH_MASK;
                    const float4 e = *reinterpret_cast<const float4*>(
                        emb + ((size_t)l * HASH_T + idx) * 4u);
                    float wgt = wx[cx] * wy[cy] * wz[cz];
                    a0 += wgt * e.x; a1 += wgt * e.y; a2 += wgt * e.z; a3 += wgt * e.w;
                }
                a0 *= wl; a1 *= wl; a2 *= wl; a3 *= wl;
            }
            // butterfly reduce over n (lane bits 0..2); inactive lanes hold 0
            #pragma unroll
            for (int m = 1; m < 8; m <<= 1) {
                a0 += __shfl_xor(a0, m);
                a1 += __shfl_xor(a1, m);
                a2 += __shfl_xor(a2, m);
                a3 += __shfl_xor(a3, m);
            }
            if (n == 0) {
                float o[4] = { a0 * inv6, a1 * inv6, a2 * inv6, a3 * inv6 };
                us4 H, L;
                #pragma unroll
                for (int q = 0; q < 4; ++q) {
                    unsigned short h, lo; split2(o[q], h, lo);
                    H[q] = h; L[q] = lo;
                }
                *reinterpret_cast<us4*>(&sAhi[s][l * 4]) = H;
                *reinterpret_cast<us4*>(&sAlo[s][l * 4]) = L;
            }
        }
    }
    __syncthreads();

    // ---- phase 2: per-ray dir-enc + bias tables (rank-27 correction)
    {
        int c = t;
        float a0 = bv0[c], a1 = bv1[c];
        #pragma unroll 3
        for (int k = 0; k < 27; ++k) {
            float dv = sDe[k];
            a0 += dv * Wv0[(256 + k) * 256 + c];
            a1 += dv * Wv1[(512 + k) * 256 + c];
        }
        sDv0[c] = a0; sDv1[c] = a1;
    }
    __syncthreads();

    // ---- phase 3 (L0): feat @ Wd0 -> act0 (cols 0..63), relu
    {
        f32x4 acc[1][2] = {};
        gemm32<2, 1>(pk, 4, w, 0, sAhi, sAlo, lane, acc);
        __syncthreads();                 // feat reads done before overwrite
        epi32<1, true>(acc, w, lane, bd0, 0, sAhi, sAlo);
    }
    __syncthreads();

    // ---- phase 4 (L1): act0 @ Wd1 -> x (cols 64..319); density from col 0
    {
        f32x4 acc[4][2] = {};
        gemm32<2, 4>(pk + 8192, 16, w * 4, 0, sAhi, sAlo, lane, acc);
        if (w == 0 && (lane >> 4) == 0) {
            #pragma unroll
            for (int st = 0; st < 2; ++st) {
                float x0 = acc[0][st][0] + bd1[0];
                int s = st * 16 + (lane & 15);
                float vv = x0 - 1.0f;
                outD[base + s] = fmaxf(vv, 0.0f) + log1pf(expf(-fabsf(vv)));
            }
        }
        __syncthreads();                 // act0 reads done (paranoia barrier)
        epi32<4, false>(acc, w * 4, lane, bd1, 64, sAhi, sAlo);
    }
    __syncthreads();

    // ---- phase 5: px = x @ Wv1[x-rows] (L3 partial, registers only)
    f32x4 px[4][2] = {};
    gemm32<8, 4>(pk + 172032, 16, w * 4, 64, sAhi, sAlo, lane, px);
    __syncthreads();

    // ---- phase 6 (L2): x @ Wv0 + sDv0 -> h2 (cols 64..319, overwrites x)
    {
        f32x4 acc[4][2] = {};
        gemm32<8, 4>(pk + 40960, 16, w * 4, 64, sAhi, sAlo, lane, acc);
        __syncthreads();                 // all x reads (phase5+6) done
        epi32<4, true>(acc, w * 4, lane, sDv0, 64, sAhi, sAlo);
    }
    __syncthreads();

    // ---- phase 7 (L3): px + h2 @ Wv1[h2-rows] + sDv1 -> h3 (cols 64..319)
    {
        gemm32<8, 4>(pk + 303104, 16, w * 4, 64, sAhi, sAlo, lane, px);
        __syncthreads();                 // h2 reads done before overwrite
        epi32<4, true>(px, w * 4, lane, sDv1, 64, sAhi, sAlo);
    }
    __syncthreads();

    // ---- phase 8 (L4): rgb = sigmoid(h3 @ Wr + br)*1.002 - 0.001
    {
        int s = t >> 3, j = t & 7, k0 = 64 + j * 32;
        float p0 = 0.f, p1 = 0.f, p2 = 0.f;
        #pragma unroll 2
        for (int q = 0; q < 4; ++q) {
            us4 vh[2], vl[2];
            *reinterpret_cast<uint4*>(vh) = *reinterpret_cast<const uint4*>(&sAhi[s][k0 + q * 8]);
            *reinterpret_cast<uint4*>(vl) = *reinterpret_cast<const uint4*>(&sAlo[s][k0 + q * 8]);
            #pragma unroll
            for (int e = 0; e < 8; ++e) {
                int k = j * 32 + q * 8 + e;
                float hv = bf16f(((const unsigned short*)vh)[e]) + bf16f(((const unsigned short*)vl)[e]);
                p0 += hv * Wr[k * 3 + 0];
                p1 += hv * Wr[k * 3 + 1];
                p2 += hv * Wr[k * 3 + 2];
            }
        }
        #pragma unroll
        for (int m = 1; m < 8; m <<= 1) {
            p0 += __shfl_xor(p0, m);
            p1 += __shfl_xor(p1, m);
            p2 += __shfl_xor(p2, m);
        }
        if (j < 3) {
            float a = ((j == 0) ? p0 : (j == 1) ? p1 : p2) + br[j];
            float sg = 1.0f / (1.0f + expf(-a));
            outRGB[(size_t)(base + s) * 3 + j] = sg * 1.002f - 0.001f;
        }
    }
}

extern "C" void kernel_launch(void* const* d_in, const int* in_sizes, int n_in,
                              void* d_out, int out_size, void* d_ws, size_t ws_size,
                              hipStream_t stream) {
    const float* means = (const float*)d_in[1];
    const float* stds_ = (const float*)d_in[2];
    const float* vdirs = (const float*)d_in[3];
    const float* emb   = (const float*)d_in[4];
    const float* Wd0 = (const float*)d_in[5];
    const float* bd0 = (const float*)d_in[6];
    const float* Wd1 = (const float*)d_in[7];
    const float* bd1 = (const float*)d_in[8];
    const float* Wv0 = (const float*)d_in[9];
    const float* bv0 = (const float*)d_in[10];
    const float* Wv1 = (const float*)d_in[11];
    const float* bv1 = (const float*)d_in[12];
    const float* Wr  = (const float*)d_in[13];
    const float* br  = (const float*)d_in[14];

    const int B  = in_sizes[3] / 3;   // 1024 rays
    const int NS = B * 32;            // 32768 samples

    unsigned short* pk = (unsigned short*)d_ws;   // 424*1024 bf16 pairs = 868 KB

    hipLaunchKernelGGL(pack_weights_kernel, dim3((424 * 512 + 255) / 256), dim3(256), 0, stream,
                       Wd0, Wd1, Wv0, Wv1, pk);

    float* outD   = (float*)d_out;
    float* outRGB = outD + NS;
    hipLaunchKernelGGL(zip_fused_kernel, dim3(B), dim3(256), 0, stream,
                       means, stds_, vdirs, emb, pk,
                       bd0, bd1, Wv0, bv0, Wv1, bv1, Wr, br,
                       outD, outRGB);
}